// Round 15
// baseline (566.473 us; speedup 1.0000x reference)
//
#include <hip/hip_runtime.h>
#include <stdint.h>

typedef unsigned short UST;
typedef __attribute__((ext_vector_type(8))) short    bf16x8;
typedef __attribute__((ext_vector_type(4))) float    f32x4;
typedef __attribute__((ext_vector_type(16))) float   f32x16;
typedef __attribute__((ext_vector_type(4))) float    float4_t;
typedef __attribute__((ext_vector_type(4))) UST      ushort4_t;
typedef __attribute__((ext_vector_type(8))) UST      ushort8_t;

__device__ __forceinline__ UST f2bf(float f) {
    union { float f; uint32_t u; } c; c.f = f;
    uint32_t u = c.u;
    u = (u + 0x7FFFu + ((u >> 16) & 1u)) >> 16;
    return (UST)u;
}
__device__ __forceinline__ float bf2f(UST h) {
    union { uint32_t u; float f; } c; c.u = ((uint32_t)h) << 16;
    return c.f;
}

__device__ __forceinline__ void async_copy16(const void* g, void* l) {
    __builtin_amdgcn_global_load_lds(
        (const __attribute__((address_space(1))) uint32_t*)g,
        (__attribute__((address_space(3))) uint32_t*)l, 16, 0, 0);
}

// bijective XCD-aware block remap (nwg % 8 == 0 in all our grids)
__device__ __forceinline__ void xcd_remap(int& bx, int& by, int& bz) {
    const int gx = (int)gridDim.x, gy = (int)gridDim.y, gz = (int)gridDim.z;
    const int nwg = gx * gy * gz;
    if (nwg & 7) return;
    int flat = ((int)blockIdx.z * gy + (int)blockIdx.y) * gx + (int)blockIdx.x;
    const int q = nwg >> 3;
    int s = (flat & 7) * q + (flat >> 3);
    bx = s % gx; s /= gx;
    by = s % gy;
    bz = s / gy;
}

// ---------------------------------------------------------------------------
// split fp32 -> hi bf16 + lo bf16 (x = hi + lo + O(2^-16))
// ---------------------------------------------------------------------------
__global__ void split_kernel(const float* __restrict__ in, UST* __restrict__ hi,
                             UST* __restrict__ lo, int n4) {
    int i = blockIdx.x * blockDim.x + threadIdx.x;
    int stride = gridDim.x * blockDim.x;
    for (; i < n4; i += stride) {
        float4_t v = *(const float4_t*)(in + (size_t)i * 4);
        ushort4_t h, l;
#pragma unroll
        for (int j = 0; j < 4; j++) {
            float f = v[j];
            UST hh = f2bf(f);
            h[j] = hh;
            l[j] = f2bf(f - bf2f(hh));
        }
        *(ushort4_t*)(hi + (size_t)i * 4) = h;
        *(ushort4_t*)(lo + (size_t)i * 4) = l;
    }
}

__global__ void cvt_hi_kernel(const float* __restrict__ in, UST* __restrict__ hi, int n4) {
    int i = blockIdx.x * blockDim.x + threadIdx.x;
    int stride = gridDim.x * blockDim.x;
    for (; i < n4; i += stride) {
        float4_t v = *(const float4_t*)(in + (size_t)i * 4);
        ushort4_t h;
#pragma unroll
        for (int j = 0; j < 4; j++) h[j] = f2bf(v[j]);
        *(ushort4_t*)(hi + (size_t)i * 4) = h;
    }
}

// ---------------------------------------------------------------------------
// 3-term split-precision GEMM, 256x256 tile, 512 threads (8 waves, 2M x 4N),
// now on v_mfma_f32_32x32x16_bf16 (m119: 1015 vs 844 FLOP/cyc/SIMD, and
// half the instruction count) with R12's verified 6-phase counted-vmcnt
// schedule (same stage order Ah,Al,Bh,Bl; vmcnt(4)@P2 certifies Bl(t);
// vmcnt(2)@P6 certifies Ah,Al,Bh(t+1); every wait precedes a barrier).
// Per-wave tile 128x64 = 4 m-frags x 2 n-frags of 32; K-step 32 = 2 k-halves.
// Frag maps (32x32x16): A/B lane: row|col = lane&31, k = (lane>>5)*8 + e.
// C/D (HW-verified m74/m101): col = lane&31, row = (reg&3)+8*(reg>>2)+4*(lane>>5).
// LDS [256][32] XOR-swizzled (slot s of row r at s^((r>>1)&3)) — frag reads
// cover all 32 banks exactly once per 8 rows -> conflict-free.
// OUT_MODE: 0 = fp32 ; 1 = split bf16 (hi C0, lo C1)
// ---------------------------------------------------------------------------
template <int OUT_MODE, bool HAS_BIAS>
__global__ __launch_bounds__(512, 2)
void gemm3_256(const UST* __restrict__ Ah, const UST* __restrict__ Al,
               const UST* __restrict__ Bh, const UST* __restrict__ Bl,
               const float* __restrict__ bias,
               void* __restrict__ C0, void* __restrict__ C1,
               int K, int ldc,
               long long sA, long long sB, long long sC) {
    constexpr int TILE = 8192;           // UST per sub-tile (256 rows x 32)
    constexpr int HALF = 4 * TILE;       // Ah|Al|Bh|Bl = 64 KiB
    __shared__ UST lds[2 * HALF];        // 128 KiB double buffer

    int bx = (int)blockIdx.x, by = (int)blockIdx.y, bz = (int)blockIdx.z;
    xcd_remap(bx, by, bz);
    const int brow = by * 256;
    const int bcol = bx * 256;

    const int t = threadIdx.x;           // 0..511
    const int wave = t >> 6, lane = t & 63;
    const int wr = (wave >> 2) * 128;    // 2 M-waves, 4 frags of 32 rows each
    const int wc = (wave & 3) * 64;      // 4 N-waves, 2 frags of 32 cols each
    const int l31 = lane & 31, hi = lane >> 5;

    const int srow0 = t >> 2;                                 // 0..127
    const int scol_sw = (((t & 3) ^ ((srow0 >> 1) & 3))) * 8; // pre-swizzled src col

    // 32x32x16 swizzled ds_read offsets (UST units, relative to sub-tile base)
    int offA32[4][2], offB32[2][2];
#pragma unroll
    for (int mf = 0; mf < 4; mf++)
#pragma unroll
        for (int kk = 0; kk < 2; kk++) {
            int r = wr + mf * 32 + l31;
            int s = kk * 2 + hi;
            offA32[mf][kk] = r * 32 + ((s ^ ((r >> 1) & 3)) << 3);
        }
#pragma unroll
    for (int nf = 0; nf < 2; nf++)
#pragma unroll
        for (int kk = 0; kk < 2; kk++) {
            int c = wc + nf * 32 + l31;
            int s = kk * 2 + hi;
            offB32[nf][kk] = c * 32 + ((s ^ ((c >> 1) & 3)) << 3);
        }

    f32x16 acc[4][2];
#pragma unroll
    for (int mf = 0; mf < 4; mf++)
#pragma unroll
        for (int nf = 0; nf < 2; nf++)
#pragma unroll
            for (int j = 0; j < 16; j++) acc[mf][nf][j] = 0.f;

    const UST* pAh = Ah + (long long)bz * sA;
    const UST* pAl = Al + (long long)bz * sA;
    const UST* pBh = Bh + (long long)bz * sB;
    const UST* pBl = Bl + (long long)bz * sB;

    auto stage2 = [&](const UST* g, UST* dst) {
        async_copy16(g, dst + t * 8);
        async_copy16(g + (size_t)128 * K, dst + 4096 + t * 8);
    };
    const size_t arow = (size_t)(brow + srow0) * (size_t)K + scol_sw;
    const size_t brow_ = (size_t)(bcol + srow0) * (size_t)K + scol_sw;

    // prologue: stage tile 0, certify all but Bl (stays in flight), release
    stage2(pAh + arow, lds);
    stage2(pAl + arow, lds + TILE);
    stage2(pBh + brow_, lds + 2 * TILE);
    stage2(pBl + brow_, lds + 3 * TILE);
    asm volatile("s_waitcnt vmcnt(2)" ::: "memory");
    __builtin_amdgcn_sched_barrier(0);
    __builtin_amdgcn_s_barrier();

    int cur = 0;
    const int nt = K / 32;
    for (int it = 0; it < nt; ++it) {
        UST* buf  = lds + cur * HALF;
        UST* nbuf = lds + (cur ^ 1) * HALF;
        const bool pf = (it + 1 < nt);
        const int k1 = (it + 1) * 32;

        bf16x8 ah0[4], ah1[4], al_[4], bh_[2][2], bl_[2][2];

        // ---- P1: read ah(kk0) x4 + bh(all) x4 ; stage Ah(t+1) ; T1-kk0
#pragma unroll
        for (int mf = 0; mf < 4; mf++) ah0[mf] = *(const bf16x8*)(buf + offA32[mf][0]);
#pragma unroll
        for (int nf = 0; nf < 2; nf++)
#pragma unroll
            for (int kk = 0; kk < 2; kk++)
                bh_[nf][kk] = *(const bf16x8*)(buf + 2 * TILE + offB32[nf][kk]);
        if (pf) stage2(pAh + arow + k1, nbuf);
        __builtin_amdgcn_s_barrier();
        asm volatile("s_waitcnt lgkmcnt(0)" ::: "memory");
        __builtin_amdgcn_sched_barrier(0);
        __builtin_amdgcn_s_setprio(1);
#pragma unroll
        for (int mf = 0; mf < 4; mf++)
#pragma unroll
            for (int nf = 0; nf < 2; nf++)
                acc[mf][nf] = __builtin_amdgcn_mfma_f32_32x32x16_bf16(ah0[mf], bh_[nf][0], acc[mf][nf], 0, 0, 0);
        __builtin_amdgcn_s_setprio(0);

        // ---- P2: read al(kk0) ; stage Al(t+1) ; vmcnt(4) certifies Bl(t) ; T3-kk0
#pragma unroll
        for (int mf = 0; mf < 4; mf++) al_[mf] = *(const bf16x8*)(buf + TILE + offA32[mf][0]);
        if (pf) {
            stage2(pAl + arow + k1, nbuf + TILE);
            asm volatile("s_waitcnt vmcnt(4)" ::: "memory");
        } else {
            asm volatile("s_waitcnt vmcnt(0)" ::: "memory");
        }
        __builtin_amdgcn_s_barrier();
        asm volatile("s_waitcnt lgkmcnt(0)" ::: "memory");
        __builtin_amdgcn_sched_barrier(0);
        __builtin_amdgcn_s_setprio(1);
#pragma unroll
        for (int mf = 0; mf < 4; mf++)
#pragma unroll
            for (int nf = 0; nf < 2; nf++)
                acc[mf][nf] = __builtin_amdgcn_mfma_f32_32x32x16_bf16(al_[mf], bh_[nf][0], acc[mf][nf], 0, 0, 0);
        __builtin_amdgcn_s_setprio(0);

        // ---- P3: read bl(all) (certified @P2) ; stage Bh(t+1) ; T2-kk0
#pragma unroll
        for (int nf = 0; nf < 2; nf++)
#pragma unroll
            for (int kk = 0; kk < 2; kk++)
                bl_[nf][kk] = *(const bf16x8*)(buf + 3 * TILE + offB32[nf][kk]);
        if (pf) stage2(pBh + brow_ + k1, nbuf + 2 * TILE);
        __builtin_amdgcn_s_barrier();
        asm volatile("s_waitcnt lgkmcnt(0)" ::: "memory");
        __builtin_amdgcn_sched_barrier(0);
        __builtin_amdgcn_s_setprio(1);
#pragma unroll
        for (int mf = 0; mf < 4; mf++)
#pragma unroll
            for (int nf = 0; nf < 2; nf++)
                acc[mf][nf] = __builtin_amdgcn_mfma_f32_32x32x16_bf16(ah0[mf], bl_[nf][0], acc[mf][nf], 0, 0, 0);
        __builtin_amdgcn_s_setprio(0);

        // ---- P4: read ah(kk1) ; stage Bl(t+1) ; T1-kk1
#pragma unroll
        for (int mf = 0; mf < 4; mf++) ah1[mf] = *(const bf16x8*)(buf + offA32[mf][1]);
        if (pf) stage2(pBl + brow_ + k1, nbuf + 3 * TILE);
        __builtin_amdgcn_s_barrier();
        asm volatile("s_waitcnt lgkmcnt(0)" ::: "memory");
        __builtin_amdgcn_sched_barrier(0);
        __builtin_amdgcn_s_setprio(1);
#pragma unroll
        for (int mf = 0; mf < 4; mf++)
#pragma unroll
            for (int nf = 0; nf < 2; nf++)
                acc[mf][nf] = __builtin_amdgcn_mfma_f32_32x32x16_bf16(ah1[mf], bh_[nf][1], acc[mf][nf], 0, 0, 0);
        __builtin_amdgcn_s_setprio(0);

        // ---- P5: read al(kk1) ; T3-kk1
#pragma unroll
        for (int mf = 0; mf < 4; mf++) al_[mf] = *(const bf16x8*)(buf + TILE + offA32[mf][1]);
        __builtin_amdgcn_s_barrier();
        asm volatile("s_waitcnt lgkmcnt(0)" ::: "memory");
        __builtin_amdgcn_sched_barrier(0);
        __builtin_amdgcn_s_setprio(1);
#pragma unroll
        for (int mf = 0; mf < 4; mf++)
#pragma unroll
            for (int nf = 0; nf < 2; nf++)
                acc[mf][nf] = __builtin_amdgcn_mfma_f32_32x32x16_bf16(al_[mf], bh_[nf][1], acc[mf][nf], 0, 0, 0);
        __builtin_amdgcn_s_setprio(0);

        // ---- P6: vmcnt(2) certifies Ah,Al,Bh(t+1); Bl(t+1) in flight ; T2-kk1
        if (pf) {
            asm volatile("s_waitcnt vmcnt(2)" ::: "memory");
        }
        __builtin_amdgcn_sched_barrier(0);
        __builtin_amdgcn_s_barrier();
        __builtin_amdgcn_s_setprio(1);
#pragma unroll
        for (int mf = 0; mf < 4; mf++)
#pragma unroll
            for (int nf = 0; nf < 2; nf++)
                acc[mf][nf] = __builtin_amdgcn_mfma_f32_32x32x16_bf16(ah1[mf], bl_[nf][1], acc[mf][nf], 0, 0, 0);
        __builtin_amdgcn_s_setprio(0);

        cur ^= 1;
    }

    float bvv[2];
#pragma unroll
    for (int nf = 0; nf < 2; nf++)
        bvv[nf] = HAS_BIAS ? bias[bcol + wc + nf * 32 + l31] : 0.0f;

#pragma unroll
    for (int mf = 0; mf < 4; mf++) {
#pragma unroll
        for (int nf = 0; nf < 2; nf++) {
            const int col = bcol + wc + nf * 32 + l31;
#pragma unroll
            for (int reg = 0; reg < 16; reg++) {
                const int row = brow + wr + mf * 32 + (reg & 3) + ((reg >> 2) << 3) + (hi << 2);
                if constexpr (OUT_MODE == 0) {
                    float* C = (float*)C0 + (long long)bz * sC;
                    C[(size_t)row * ldc + col] = acc[mf][nf][reg] + bvv[nf];
                } else {
                    UST* Hh = (UST*)C0 + (long long)bz * sC;
                    UST* Ll = (UST*)C1 + (long long)bz * sC;
                    float v = acc[mf][nf][reg] + bvv[nf];
                    UST h = f2bf(v);
                    Hh[(size_t)row * ldc + col] = h;
                    Ll[(size_t)row * ldc + col] = f2bf(v - bf2f(h));
                }
            }
        }
    }
}

// ---------------------------------------------------------------------------
// 1-term GEMM, 128x128 tile (round-6 verified): C[M,N] = A[M,K]*B[N,K]^T.
// OUT_MODE: 0 = fp32 ; 2 = bf16 transposed (LDS-bounce, coalesced)
// ---------------------------------------------------------------------------
template <int OUT_MODE, bool HAS_BIAS>
__global__ __launch_bounds__(256, 2)
void gemm_bt(const UST* __restrict__ Aptr, const UST* __restrict__ Bptr,
             const float* __restrict__ bias,
             void* __restrict__ C0,
             int K, int ldc,
             long long sA, long long sB, long long sC) {
    constexpr int HALF = 8192;           // A 4096 + B 4096 UST
    __shared__ UST lds[16384];           // dbuf; epilogue bounce reuses 32 KB

    int bx = (int)blockIdx.x, by = (int)blockIdx.y, bz = (int)blockIdx.z;
    xcd_remap(bx, by, bz);
    const int brow = by * 128;
    const int bcol = bx * 128;

    const int t = threadIdx.x;
    const int wave = t >> 6, lane = t & 63;
    const int wr = (wave >> 1) * 64, wc = (wave & 1) * 64;
    const int lr = lane & 15, lg = lane >> 4;

    const int srow = t >> 2;                                  // 0..63
    const int scol_sw = (((t & 3) ^ ((srow >> 1) & 3))) * 8;

    int offA[4], offB[4];
#pragma unroll
    for (int m = 0; m < 4; m++) {
        int r = wr + m * 16 + lr;
        offA[m] = r * 32 + ((lg ^ ((r >> 1) & 3)) << 3);
    }
#pragma unroll
    for (int n = 0; n < 4; n++) {
        int r = wc + n * 16 + lr;
        offB[n] = r * 32 + ((lg ^ ((r >> 1) & 3)) << 3);
    }

    f32x4 acc[4][4];
#pragma unroll
    for (int m = 0; m < 4; m++)
#pragma unroll
        for (int n = 0; n < 4; n++) acc[m][n] = (f32x4){0.f, 0.f, 0.f, 0.f};

    const UST* Ah = Aptr + (long long)bz * sA;
    const UST* Bh = Bptr + (long long)bz * sB;

    auto stage = [&](UST* dst, int k0) {
        const UST* gA = Ah + (size_t)(brow + srow) * (size_t)K + k0 + scol_sw;
        async_copy16(gA, dst + t * 8);
        async_copy16(gA + (size_t)64 * K, dst + 2048 + t * 8);
        const UST* gB = Bh + (size_t)(bcol + srow) * (size_t)K + k0 + scol_sw;
        async_copy16(gB, dst + 4096 + t * 8);
        async_copy16(gB + (size_t)64 * K, dst + 6144 + t * 8);
    };

    stage(lds, 0);
    int cur = 0;
    const int nt = K / 32;
    for (int it = 0; it < nt; ++it) {
        UST* buf = lds + cur * HALF;
        __builtin_amdgcn_s_barrier();            // barA
        if (it + 1 < nt) {
            stage(lds + (cur ^ 1) * HALF, (it + 1) * 32);
            asm volatile("s_waitcnt vmcnt(4)" ::: "memory");
        } else {
            asm volatile("s_waitcnt vmcnt(0)" ::: "memory");
        }
        __builtin_amdgcn_sched_barrier(0);
        __builtin_amdgcn_s_barrier();            // barB

        bf16x8 ah[4], bh[4];
#pragma unroll
        for (int m = 0; m < 4; m++) ah[m] = *(const bf16x8*)(buf + offA[m]);
#pragma unroll
        for (int n = 0; n < 4; n++) bh[n] = *(const bf16x8*)(buf + 4096 + offB[n]);

        __builtin_amdgcn_s_setprio(1);
#pragma unroll
        for (int m = 0; m < 4; m++)
#pragma unroll
            for (int n = 0; n < 4; n++)
                acc[m][n] = __builtin_amdgcn_mfma_f32_16x16x32_bf16(ah[m], bh[n], acc[m][n], 0, 0, 0);
        __builtin_amdgcn_s_setprio(0);
        cur ^= 1;
    }

    float bvv[4];
#pragma unroll
    for (int n = 0; n < 4; n++)
        bvv[n] = HAS_BIAS ? bias[bcol + wc + n * 16 + lr] : 0.0f;

    if constexpr (OUT_MODE == 2) {
        __syncthreads();   // all waves done with K-loop LDS before overwrite
#pragma unroll
        for (int m = 0; m < 4; m++) {
            const int r0 = wr + m * 16 + lg * 4;
#pragma unroll
            for (int n = 0; n < 4; n++) {
                const int c = wc + n * 16 + lr;
                ushort4_t pk;
#pragma unroll
                for (int j = 0; j < 4; j++) pk[j] = f2bf(acc[m][n][j] + bvv[n]);
                *(ushort4_t*)(lds + c * 128 + r0) = pk;
            }
        }
        __syncthreads();
        UST* V = (UST*)C0 + (long long)bz * sC;
        const int hl = t >> 1, soff = (t & 1) * 64;
        const UST* src = lds + hl * 128 + soff;
        UST* dst = V + (size_t)(bcol + hl) * ldc + brow + soff;
#pragma unroll
        for (int i = 0; i < 8; i++)
            *(ushort8_t*)(dst + i * 8) = *(const ushort8_t*)(src + i * 8);
        return;
    }

#pragma unroll
    for (int m = 0; m < 4; m++) {
        const int row0 = brow + wr + m * 16 + lg * 4;
#pragma unroll
        for (int n = 0; n < 4; n++) {
            const int col = bcol + wc + n * 16 + lr;
            float* C = (float*)C0 + (long long)bz * sC;
#pragma unroll
            for (int j = 0; j < 4; j++)
                C[(size_t)(row0 + j) * ldc + col] = acc[m][n][j] + bvv[n];
        }
    }
}

// ---------------------------------------------------------------------------
// row softmax over 2048 fp32 -> bf16 probs. One block (256 thr) per row.
// ---------------------------------------------------------------------------
__global__ __launch_bounds__(256)
void softmax_bf16(const float* __restrict__ S, UST* __restrict__ P) {
    const size_t row = blockIdx.x;
    const float* s = S + row * 2048;
    const int t = threadIdx.x;
    const int wave = t >> 6, lane = t & 63;

    float4_t v0 = *(const float4_t*)(s + t * 8);
    float4_t v1 = *(const float4_t*)(s + t * 8 + 4);
    float vv[8];
#pragma unroll
    for (int j = 0; j < 4; j++) { vv[j] = v0[j]; vv[4 + j] = v1[j]; }

    float m = vv[0];
#pragma unroll
    for (int j = 1; j < 8; j++) m = fmaxf(m, vv[j]);
#pragma unroll
    for (int off = 32; off; off >>= 1) m = fmaxf(m, __shfl_xor(m, off));

    __shared__ float red[16];
    if (lane == 0) red[wave] = m;
    __syncthreads();
    m = fmaxf(fmaxf(red[0], red[1]), fmaxf(red[2], red[3]));

    float e[8];
    float sum = 0.f;
#pragma unroll
    for (int j = 0; j < 8; j++) { e[j] = __expf(vv[j] - m); sum += e[j]; }
#pragma unroll
    for (int off = 32; off; off >>= 1) sum += __shfl_xor(sum, off);
    if (lane == 0) red[8 + wave] = sum;
    __syncthreads();
    sum = red[8] + red[9] + red[10] + red[11];

    float inv = 1.0f / sum;
    ushort8_t pk;
#pragma unroll
    for (int j = 0; j < 8; j++) pk[j] = f2bf(e[j] * inv);
    *(ushort8_t*)(P + row * 2048 + t * 8) = pk;
}

// ---------------------------------------------------------------------------
extern "C" void kernel_launch(void* const* d_in, const int* in_sizes, int n_in,
                              void* d_out, int out_size, void* d_ws, size_t ws_size,
                              hipStream_t stream) {
    (void)in_sizes; (void)n_in; (void)out_size;
    const float* x  = (const float*)d_in[0];
    const float* Wq = (const float*)d_in[1];
    const float* bq = (const float*)d_in[2];
    const float* Wk = (const float*)d_in[3];
    const float* bk = (const float*)d_in[4];
    const float* Wv = (const float*)d_in[5];
    const float* bv = (const float*)d_in[6];
    float* out = (float*)d_out;

    const int B = 8, S = 2048, H = 1024;
    const size_t BSH = (size_t)B * S * H;   // 16,777,216
    const long long sXH = (long long)S * H; // 2,097,152

    char* p = (char*)d_ws;
    UST* qh = (UST*)p; p += BSH * 2;
    UST* ql = (UST*)p; p += BSH * 2;
    UST* kh = (UST*)p; p += BSH * 2;
    UST* kl = (UST*)p; p += BSH * 2;
    UST* vt = (UST*)p; p += BSH * 2;   // [B][H][S]

    const size_t fixed = (size_t)(p - (char*)d_ws);           // 160 MiB
    const size_t perB = (size_t)S * S * 6;                    // 24 MiB/batch
    const size_t avail = ws_size > fixed ? ws_size - fixed : 0;

    const size_t HH = (size_t)H * H;

    // tail region: split inputs (dead after projections; scores alias them)
    char* q = p;
    UST* xh  = (UST*)q; q += BSH * 2;
    UST* xl  = (UST*)q; q += BSH * 2;
    UST* wqh = (UST*)q; q += HH * 2;
    UST* wql = (UST*)q; q += HH * 2;
    UST* wkh = (UST*)q; q += HH * 2;
    UST* wkl = (UST*)q; q += HH * 2;
    UST* wvh = (UST*)q; q += HH * 2;

    dim3 blk(256);
    dim3 blk512(512);

    // 1. splits
    split_kernel<<<2048, blk, 0, stream>>>(x, xh, xl, (int)(BSH / 4));
    split_kernel<<<256, blk, 0, stream>>>(Wq, wqh, wql, (int)(HH / 4));
    split_kernel<<<256, blk, 0, stream>>>(Wk, wkh, wkl, (int)(HH / 4));
    cvt_hi_kernel<<<256, blk, 0, stream>>>(Wv, wvh, (int)(HH / 4));

    // 2. projections: q,k 3-term 256^2; v 1-term 128^2 transposed out
    dim3 gproj3(H / 256, S / 256, B);   // (4,8,8) = 256 blocks
    gemm3_256<1, true><<<gproj3, blk512, 0, stream>>>(
        xh, xl, wqh, wql, bq, qh, ql, H, H, sXH, 0, sXH);
    gemm3_256<1, true><<<gproj3, blk512, 0, stream>>>(
        xh, xl, wkh, wkl, bk, kh, kl, H, H, sXH, 0, sXH);
    dim3 gprojv(H / 128, S / 128, B);   // (8,16,8)
    gemm_bt<2, true><<<gprojv, blk, 0, stream>>>(
        xh, wvh, bv, vt, H, S, sXH, 0, (long long)H * S);

    // 3. attention per batch-group
    int g = (int)(avail / perB);
    if (g >= 1) {
        if (g > 8) g = 8;
        while (8 % g) g--;
        float* scores = (float*)p;            // aliases split bufs (dead now)
        UST* probs = (UST*)(p + (size_t)g * S * S * 4);

        for (int b0 = 0; b0 < B; b0 += g) {
            const size_t ob = (size_t)b0 * S * H;
            dim3 gsc(S / 256, S / 256, g);    // (8,8,g)
            gemm3_256<0, false><<<gsc, blk512, 0, stream>>>(
                qh + ob, ql + ob, kh + ob, kl + ob, nullptr,
                scores, nullptr, H, S, sXH, sXH, (long long)S * S);

            softmax_bf16<<<g * S, blk, 0, stream>>>(scores, probs);

            dim3 gpv(H / 128, S / 128, g);
            gemm_bt<0, false><<<gpv, blk, 0, stream>>>(
                probs, vt + (size_t)b0 * H * S, nullptr,
                out + ob, S, H,
                (long long)S * S, (long long)H * S, sXH);
        }
    } else {
        // tight-workspace fallback: per-batch row-chunked scores (256-row grain)
        int rows = (int)(avail / ((size_t)S * 6 * 256)) * 256;
        if (rows < 256) rows = 256;
        if (rows > S) rows = S;
        float* scores = (float*)p;
        UST* probs = (UST*)(p + (size_t)rows * S * 4);

        for (int b = 0; b < B; b++) {
            for (int r0 = 0; r0 < S; r0 += rows) {
                int rc = S - r0 < rows ? S - r0 : rows;
                const size_t ob = (size_t)b * S * H + (size_t)r0 * H;
                dim3 gsc(S / 256, rc / 256, 1);
                gemm3_256<0, false><<<gsc, blk512, 0, stream>>>(
                    qh + ob, ql + ob, kh + (size_t)b * S * H, kl + (size_t)b * S * H,
                    nullptr, scores, nullptr, H, S, 0, 0, 0);

                softmax_bf16<<<rc, blk, 0, stream>>>(scores, probs);

                dim3 gpv(H / 128, rc / 128, 1);
                gemm_bt<0, false><<<gpv, blk, 0, stream>>>(
                    probs, vt + (size_t)b * H * S, nullptr,
                    out + ob, S, H, 0, 0, 0);
            }
        }
    }
}

// Round 16
// 527.341 us; speedup vs baseline: 1.0742x; 1.0742x over previous
//
#include <hip/hip_runtime.h>
#include <stdint.h>

typedef unsigned short UST;
typedef __attribute__((ext_vector_type(8))) short    bf16x8;
typedef __attribute__((ext_vector_type(4))) float    f32x4;
typedef __attribute__((ext_vector_type(4))) float    float4_t;
typedef __attribute__((ext_vector_type(4))) UST      ushort4_t;
typedef __attribute__((ext_vector_type(8))) UST      ushort8_t;

__device__ __forceinline__ UST f2bf(float f) {
    union { float f; uint32_t u; } c; c.f = f;
    uint32_t u = c.u;
    u = (u + 0x7FFFu + ((u >> 16) & 1u)) >> 16;
    return (UST)u;
}
__device__ __forceinline__ float bf2f(UST h) {
    union { uint32_t u; float f; } c; c.u = ((uint32_t)h) << 16;
    return c.f;
}

__device__ __forceinline__ void async_copy16(const void* g, void* l) {
    __builtin_amdgcn_global_load_lds(
        (const __attribute__((address_space(1))) uint32_t*)g,
        (__attribute__((address_space(3))) uint32_t*)l, 16, 0, 0);
}

// bijective XCD-aware block remap (nwg % 8 == 0 in all our grids)
__device__ __forceinline__ void xcd_remap(int& bx, int& by, int& bz) {
    const int gx = (int)gridDim.x, gy = (int)gridDim.y, gz = (int)gridDim.z;
    const int nwg = gx * gy * gz;
    if (nwg & 7) return;
    int flat = ((int)blockIdx.z * gy + (int)blockIdx.y) * gx + (int)blockIdx.x;
    const int q = nwg >> 3;
    int s = (flat & 7) * q + (flat >> 3);
    bx = s % gx; s /= gx;
    by = s % gy;
    bz = s / gy;
}

// ---------------------------------------------------------------------------
// split fp32 -> hi bf16 + lo bf16 (x = hi + lo + O(2^-16))
// ---------------------------------------------------------------------------
__global__ void split_kernel(const float* __restrict__ in, UST* __restrict__ hi,
                             UST* __restrict__ lo, int n4) {
    int i = blockIdx.x * blockDim.x + threadIdx.x;
    int stride = gridDim.x * blockDim.x;
    for (; i < n4; i += stride) {
        float4_t v = *(const float4_t*)(in + (size_t)i * 4);
        ushort4_t h, l;
#pragma unroll
        for (int j = 0; j < 4; j++) {
            float f = v[j];
            UST hh = f2bf(f);
            h[j] = hh;
            l[j] = f2bf(f - bf2f(hh));
        }
        *(ushort4_t*)(hi + (size_t)i * 4) = h;
        *(ushort4_t*)(lo + (size_t)i * 4) = l;
    }
}

__global__ void cvt_hi_kernel(const float* __restrict__ in, UST* __restrict__ hi, int n4) {
    int i = blockIdx.x * blockDim.x + threadIdx.x;
    int stride = gridDim.x * blockDim.x;
    for (; i < n4; i += stride) {
        float4_t v = *(const float4_t*)(in + (size_t)i * 4);
        ushort4_t h;
#pragma unroll
        for (int j = 0; j < 4; j++) h[j] = f2bf(v[j]);
        *(ushort4_t*)(hi + (size_t)i * 4) = h;
    }
}

// ---------------------------------------------------------------------------
// 3-term split-precision GEMM, 256x256 tile, 512 threads (8 waves, 2M x 4N),
// 6-phase interleave with COUNTED vmcnt — R12's verified best (16x16 MFMA,
// 0 bank conflicts; R15's 32x32 variant hit 6.3M conflicts -> reverted).
//   Stage order per step t (into buf^1): P1 Ah(t+1), P2 Al(t+1), P3 Bh(t+1),
//   P4 Bl(t+1)  (2 global_load_lds each).
//   Waits: P2 vmcnt(4)  -> certifies Bl(t) just before its P3 read.
//          P6 vmcnt(2)  -> certifies Ah,Al,Bh(t+1) for next step's reads.
//   Both precede a barrier (cross-wave rule). vmcnt never 0 mid-loop.
// LDS: dbuf x {Ah,Al,Bh,Bl}[256][32] = 2 x 64 KiB.  XOR swizzle as R3.
// OUT_MODE: 0 = fp32 ; 1 = split bf16 (hi C0, lo C1)
// ---------------------------------------------------------------------------
template <int OUT_MODE, bool HAS_BIAS>
__global__ __launch_bounds__(512, 2)
void gemm3_256(const UST* __restrict__ Ah, const UST* __restrict__ Al,
               const UST* __restrict__ Bh, const UST* __restrict__ Bl,
               const float* __restrict__ bias,
               void* __restrict__ C0, void* __restrict__ C1,
               int K, int ldc,
               long long sA, long long sB, long long sC) {
    constexpr int TILE = 8192;           // UST per sub-tile (256 rows x 32)
    constexpr int HALF = 4 * TILE;       // Ah|Al|Bh|Bl = 64 KiB
    __shared__ UST lds[2 * HALF];        // 128 KiB double buffer

    int bx = (int)blockIdx.x, by = (int)blockIdx.y, bz = (int)blockIdx.z;
    xcd_remap(bx, by, bz);
    const int brow = by * 256;
    const int bcol = bx * 256;

    const int t = threadIdx.x;           // 0..511
    const int wave = t >> 6, lane = t & 63;
    const int wr = (wave >> 2) * 128;    // 2 M-waves
    const int wc = (wave & 3) * 64;      // 4 N-waves
    const int lr = lane & 15, lg = lane >> 4;

    const int srow0 = t >> 2;                                 // 0..127
    const int scol_sw = (((t & 3) ^ ((srow0 >> 1) & 3))) * 8; // pre-swizzled src col

    int offA[8], offB[4];
#pragma unroll
    for (int m = 0; m < 8; m++) {
        int r = wr + m * 16 + lr;
        offA[m] = r * 32 + ((lg ^ ((r >> 1) & 3)) << 3);
    }
#pragma unroll
    for (int n = 0; n < 4; n++) {
        int r = wc + n * 16 + lr;
        offB[n] = r * 32 + ((lg ^ ((r >> 1) & 3)) << 3);
    }

    f32x4 acc[8][4];
#pragma unroll
    for (int m = 0; m < 8; m++)
#pragma unroll
        for (int n = 0; n < 4; n++) acc[m][n] = (f32x4){0.f, 0.f, 0.f, 0.f};

    const UST* pAh = Ah + (long long)bz * sA;
    const UST* pAl = Al + (long long)bz * sA;
    const UST* pBh = Bh + (long long)bz * sB;
    const UST* pBl = Bl + (long long)bz * sB;

    auto stage2 = [&](const UST* g, UST* dst) {
        async_copy16(g, dst + t * 8);
        async_copy16(g + (size_t)128 * K, dst + 4096 + t * 8);
    };
    const size_t arow = (size_t)(brow + srow0) * (size_t)K + scol_sw;
    const size_t brow_ = (size_t)(bcol + srow0) * (size_t)K + scol_sw;

    // prologue: stage tile 0 (P-order), certify all but Bl, release
    stage2(pAh + arow, lds);
    stage2(pAl + arow, lds + TILE);
    stage2(pBh + brow_, lds + 2 * TILE);
    stage2(pBl + brow_, lds + 3 * TILE);
    asm volatile("s_waitcnt vmcnt(2)" ::: "memory");
    __builtin_amdgcn_sched_barrier(0);
    __builtin_amdgcn_s_barrier();

    int cur = 0;
    const int nt = K / 32;
    for (int it = 0; it < nt; ++it) {
        UST* buf  = lds + cur * HALF;
        UST* nbuf = lds + (cur ^ 1) * HALF;
        const bool pf = (it + 1 < nt);
        const int k1 = (it + 1) * 32;

        bf16x8 ah_[4], al_[4], bh_[4], bl_[4];

        // ---- P1: read Ah[0..3] + Bh ; stage Ah(t+1)
#pragma unroll
        for (int m = 0; m < 4; m++) ah_[m] = *(const bf16x8*)(buf + offA[m]);
#pragma unroll
        for (int n = 0; n < 4; n++) bh_[n] = *(const bf16x8*)(buf + 2 * TILE + offB[n]);
        if (pf) stage2(pAh + arow + k1, nbuf);
        __builtin_amdgcn_s_barrier();
        asm volatile("s_waitcnt lgkmcnt(0)" ::: "memory");
        __builtin_amdgcn_sched_barrier(0);
        __builtin_amdgcn_s_setprio(1);
#pragma unroll
        for (int m = 0; m < 4; m++)
#pragma unroll
            for (int n = 0; n < 4; n++)
                acc[m][n] = __builtin_amdgcn_mfma_f32_16x16x32_bf16(ah_[m], bh_[n], acc[m][n], 0, 0, 0);
        __builtin_amdgcn_s_setprio(0);

        // ---- P2: read Al[0..3] ; stage Al(t+1) ; vmcnt(4) certifies Bl(t)
#pragma unroll
        for (int m = 0; m < 4; m++) al_[m] = *(const bf16x8*)(buf + TILE + offA[m]);
        if (pf) {
            stage2(pAl + arow + k1, nbuf + TILE);
            asm volatile("s_waitcnt vmcnt(4)" ::: "memory");
        } else {
            asm volatile("s_waitcnt vmcnt(0)" ::: "memory");
        }
        __builtin_amdgcn_s_barrier();
        asm volatile("s_waitcnt lgkmcnt(0)" ::: "memory");
        __builtin_amdgcn_sched_barrier(0);
        __builtin_amdgcn_s_setprio(1);
#pragma unroll
        for (int m = 0; m < 4; m++)
#pragma unroll
            for (int n = 0; n < 4; n++)
                acc[m][n] = __builtin_amdgcn_mfma_f32_16x16x32_bf16(al_[m], bh_[n], acc[m][n], 0, 0, 0);
        __builtin_amdgcn_s_setprio(0);

        // ---- P3: read Bl(t) (certified at P2) ; stage Bh(t+1) ; MFMA T2 m0-3
#pragma unroll
        for (int n = 0; n < 4; n++) bl_[n] = *(const bf16x8*)(buf + 3 * TILE + offB[n]);
        if (pf) stage2(pBh + brow_ + k1, nbuf + 2 * TILE);
        __builtin_amdgcn_s_barrier();
        asm volatile("s_waitcnt lgkmcnt(0)" ::: "memory");
        __builtin_amdgcn_sched_barrier(0);
        __builtin_amdgcn_s_setprio(1);
#pragma unroll
        for (int m = 0; m < 4; m++)
#pragma unroll
            for (int n = 0; n < 4; n++)
                acc[m][n] = __builtin_amdgcn_mfma_f32_16x16x32_bf16(ah_[m], bl_[n], acc[m][n], 0, 0, 0);
        __builtin_amdgcn_s_setprio(0);

        // ---- P4: read Ah[4..7] ; stage Bl(t+1) ; MFMA T1 m4-7
#pragma unroll
        for (int m = 0; m < 4; m++) ah_[m] = *(const bf16x8*)(buf + offA[m + 4]);
        if (pf) stage2(pBl + brow_ + k1, nbuf + 3 * TILE);
        __builtin_amdgcn_s_barrier();
        asm volatile("s_waitcnt lgkmcnt(0)" ::: "memory");
        __builtin_amdgcn_sched_barrier(0);
        __builtin_amdgcn_s_setprio(1);
#pragma unroll
        for (int m = 0; m < 4; m++)
#pragma unroll
            for (int n = 0; n < 4; n++)
                acc[m + 4][n] = __builtin_amdgcn_mfma_f32_16x16x32_bf16(ah_[m], bh_[n], acc[m + 4][n], 0, 0, 0);
        __builtin_amdgcn_s_setprio(0);

        // ---- P5: read Al[4..7] ; MFMA T3 m4-7
#pragma unroll
        for (int m = 0; m < 4; m++) al_[m] = *(const bf16x8*)(buf + TILE + offA[m + 4]);
        __builtin_amdgcn_s_barrier();
        asm volatile("s_waitcnt lgkmcnt(0)" ::: "memory");
        __builtin_amdgcn_sched_barrier(0);
        __builtin_amdgcn_s_setprio(1);
#pragma unroll
        for (int m = 0; m < 4; m++)
#pragma unroll
            for (int n = 0; n < 4; n++)
                acc[m + 4][n] = __builtin_amdgcn_mfma_f32_16x16x32_bf16(al_[m], bh_[n], acc[m + 4][n], 0, 0, 0);
        __builtin_amdgcn_s_setprio(0);

        // ---- P6: vmcnt(2) certifies Ah,Al,Bh(t+1); Bl(t+1) stays in flight.
        if (pf) {
            asm volatile("s_waitcnt vmcnt(2)" ::: "memory");
        }
        __builtin_amdgcn_sched_barrier(0);
        __builtin_amdgcn_s_barrier();
        __builtin_amdgcn_s_setprio(1);
#pragma unroll
        for (int m = 0; m < 4; m++)
#pragma unroll
            for (int n = 0; n < 4; n++)
                acc[m + 4][n] = __builtin_amdgcn_mfma_f32_16x16x32_bf16(ah_[m], bl_[n], acc[m + 4][n], 0, 0, 0);
        __builtin_amdgcn_s_setprio(0);

        cur ^= 1;
    }

    float bvv[4];
#pragma unroll
    for (int n = 0; n < 4; n++)
        bvv[n] = HAS_BIAS ? bias[bcol + wc + n * 16 + lr] : 0.0f;

#pragma unroll
    for (int m = 0; m < 8; m++) {
        const int row0 = brow + wr + m * 16 + lg * 4;
#pragma unroll
        for (int n = 0; n < 4; n++) {
            const int col = bcol + wc + n * 16 + lr;
            if constexpr (OUT_MODE == 0) {
                float* C = (float*)C0 + (long long)bz * sC;
#pragma unroll
                for (int j = 0; j < 4; j++)
                    C[(size_t)(row0 + j) * ldc + col] = acc[m][n][j] + bvv[n];
            } else {
                UST* Hh = (UST*)C0 + (long long)bz * sC;
                UST* Ll = (UST*)C1 + (long long)bz * sC;
#pragma unroll
                for (int j = 0; j < 4; j++) {
                    float v = acc[m][n][j] + bvv[n];
                    UST h = f2bf(v);
                    Hh[(size_t)(row0 + j) * ldc + col] = h;
                    Ll[(size_t)(row0 + j) * ldc + col] = f2bf(v - bf2f(h));
                }
            }
        }
    }
}

// ---------------------------------------------------------------------------
// 1-term GEMM, 128x128 tile, BK=64 (2x MFMA per barrier-pair vs R12's BK=32),
// counted-vmcnt dbuf (R6-verified shape, counts scaled x2):
//   per K-step: barA ; stage 4 subtiles {A0,A1,B0,B1}[128][32] (8 loads) ;
//   vmcnt(8) = tile-t's 8 loads (issued one full iter ago) landed, t+1's 8 in
//   flight ; barB ; read 16 frags ; 32 MFMA (k0-half then k1-half — same
//   accumulation order as BK=32 -> bit-identical).
// LDS: 2 x 32 KiB = 64 KiB -> 2 blocks/CU (matches grid residency).
// OUT_MODE: 0 = fp32 ; 2 = bf16 transposed (LDS-bounce, coalesced)
// ---------------------------------------------------------------------------
template <int OUT_MODE, bool HAS_BIAS>
__global__ __launch_bounds__(256, 2)
void gemm_bt(const UST* __restrict__ Aptr, const UST* __restrict__ Bptr,
             const float* __restrict__ bias,
             void* __restrict__ C0,
             int K, int ldc,
             long long sA, long long sB, long long sC) {
    constexpr int SUB = 4096;            // [128][32] UST
    constexpr int HALF = 4 * SUB;        // A0|A1|B0|B1 = 32 KiB
    __shared__ UST lds[2 * HALF];        // 64 KiB dbuf; bounce reuses 32 KiB

    int bx = (int)blockIdx.x, by = (int)blockIdx.y, bz = (int)blockIdx.z;
    xcd_remap(bx, by, bz);
    const int brow = by * 128;
    const int bcol = bx * 128;

    const int t = threadIdx.x;
    const int wave = t >> 6, lane = t & 63;
    const int wr = (wave >> 1) * 64, wc = (wave & 1) * 64;
    const int lr = lane & 15, lg = lane >> 4;

    const int srow = t >> 2;                                  // 0..63
    const int scol_sw = (((t & 3) ^ ((srow >> 1) & 3))) * 8;

    int offA[4], offB[4];
#pragma unroll
    for (int m = 0; m < 4; m++) {
        int r = wr + m * 16 + lr;
        offA[m] = r * 32 + ((lg ^ ((r >> 1) & 3)) << 3);
    }
#pragma unroll
    for (int n = 0; n < 4; n++) {
        int r = wc + n * 16 + lr;
        offB[n] = r * 32 + ((lg ^ ((r >> 1) & 3)) << 3);
    }

    f32x4 acc[4][4];
#pragma unroll
    for (int m = 0; m < 4; m++)
#pragma unroll
        for (int n = 0; n < 4; n++) acc[m][n] = (f32x4){0.f, 0.f, 0.f, 0.f};

    const UST* Ah = Aptr + (long long)bz * sA;
    const UST* Bh = Bptr + (long long)bz * sB;

    // stage one [128][32] sub-tile (2 loads/thread)
    auto stageSub = [&](const UST* g, UST* dst) {
        async_copy16(g, dst + t * 8);
        async_copy16(g + (size_t)64 * K, dst + 2048 + t * 8);
    };
    const size_t arow = (size_t)(brow + srow) * (size_t)K + scol_sw;
    const size_t brw = (size_t)(bcol + srow) * (size_t)K + scol_sw;

    auto stage = [&](UST* dst, int k0) {
        stageSub(Ah + arow + k0, dst);
        stageSub(Ah + arow + k0 + 32, dst + SUB);
        stageSub(Bh + brw + k0, dst + 2 * SUB);
        stageSub(Bh + brw + k0 + 32, dst + 3 * SUB);
    };

    stage(lds, 0);
    int cur = 0;
    const int nt = K / 64;
    for (int it = 0; it < nt; ++it) {
        UST* buf = lds + cur * HALF;
        __builtin_amdgcn_s_barrier();            // barA
        if (it + 1 < nt) {
            stage(lds + (cur ^ 1) * HALF, (it + 1) * 64);
            // tile-it's 8 loads (oldest) landed; t+1's 8 stay in flight
            asm volatile("s_waitcnt vmcnt(8)" ::: "memory");
        } else {
            asm volatile("s_waitcnt vmcnt(0)" ::: "memory");
        }
        __builtin_amdgcn_sched_barrier(0);
        __builtin_amdgcn_s_barrier();            // barB

        bf16x8 a0[4], a1[4], b0[4], b1[4];
#pragma unroll
        for (int m = 0; m < 4; m++) {
            a0[m] = *(const bf16x8*)(buf + offA[m]);
            a1[m] = *(const bf16x8*)(buf + SUB + offA[m]);
        }
#pragma unroll
        for (int n = 0; n < 4; n++) {
            b0[n] = *(const bf16x8*)(buf + 2 * SUB + offB[n]);
            b1[n] = *(const bf16x8*)(buf + 3 * SUB + offB[n]);
        }

        __builtin_amdgcn_s_setprio(1);
#pragma unroll
        for (int m = 0; m < 4; m++)
#pragma unroll
            for (int n = 0; n < 4; n++)
                acc[m][n] = __builtin_amdgcn_mfma_f32_16x16x32_bf16(a0[m], b0[n], acc[m][n], 0, 0, 0);
#pragma unroll
        for (int m = 0; m < 4; m++)
#pragma unroll
            for (int n = 0; n < 4; n++)
                acc[m][n] = __builtin_amdgcn_mfma_f32_16x16x32_bf16(a1[m], b1[n], acc[m][n], 0, 0, 0);
        __builtin_amdgcn_s_setprio(0);
        cur ^= 1;
    }

    float bvv[4];
#pragma unroll
    for (int n = 0; n < 4; n++)
        bvv[n] = HAS_BIAS ? bias[bcol + wc + n * 16 + lr] : 0.0f;

    if constexpr (OUT_MODE == 2) {
        __syncthreads();   // all waves done with K-loop LDS before overwrite
#pragma unroll
        for (int m = 0; m < 4; m++) {
            const int r0 = wr + m * 16 + lg * 4;
#pragma unroll
            for (int n = 0; n < 4; n++) {
                const int c = wc + n * 16 + lr;
                ushort4_t pk;
#pragma unroll
                for (int j = 0; j < 4; j++) pk[j] = f2bf(acc[m][n][j] + bvv[n]);
                *(ushort4_t*)(lds + c * 128 + r0) = pk;
            }
        }
        __syncthreads();
        UST* V = (UST*)C0 + (long long)bz * sC;
        const int hl = t >> 1, soff = (t & 1) * 64;
        const UST* src = lds + hl * 128 + soff;
        UST* dst = V + (size_t)(bcol + hl) * ldc + brow + soff;
#pragma unroll
        for (int i = 0; i < 8; i++)
            *(ushort8_t*)(dst + i * 8) = *(const ushort8_t*)(src + i * 8);
        return;
    }

#pragma unroll
    for (int m = 0; m < 4; m++) {
        const int row0 = brow + wr + m * 16 + lg * 4;
#pragma unroll
        for (int n = 0; n < 4; n++) {
            const int col = bcol + wc + n * 16 + lr;
            float* C = (float*)C0 + (long long)bz * sC;
#pragma unroll
            for (int j = 0; j < 4; j++)
                C[(size_t)(row0 + j) * ldc + col] = acc[m][n][j] + bvv[n];
        }
    }
}

// ---------------------------------------------------------------------------
// row softmax over 2048 fp32 -> bf16 probs. One block (256 thr) per row.
// ---------------------------------------------------------------------------
__global__ __launch_bounds__(256)
void softmax_bf16(const float* __restrict__ S, UST* __restrict__ P) {
    const size_t row = blockIdx.x;
    const float* s = S + row * 2048;
    const int t = threadIdx.x;
    const int wave = t >> 6, lane = t & 63;

    float4_t v0 = *(const float4_t*)(s + t * 8);
    float4_t v1 = *(const float4_t*)(s + t * 8 + 4);
    float vv[8];
#pragma unroll
    for (int j = 0; j < 4; j++) { vv[j] = v0[j]; vv[4 + j] = v1[j]; }

    float m = vv[0];
#pragma unroll
    for (int j = 1; j < 8; j++) m = fmaxf(m, vv[j]);
#pragma unroll
    for (int off = 32; off; off >>= 1) m = fmaxf(m, __shfl_xor(m, off));

    __shared__ float red[16];
    if (lane == 0) red[wave] = m;
    __syncthreads();
    m = fmaxf(fmaxf(red[0], red[1]), fmaxf(red[2], red[3]));

    float e[8];
    float sum = 0.f;
#pragma unroll
    for (int j = 0; j < 8; j++) { e[j] = __expf(vv[j] - m); sum += e[j]; }
#pragma unroll
    for (int off = 32; off; off >>= 1) sum += __shfl_xor(sum, off);
    if (lane == 0) red[8 + wave] = sum;
    __syncthreads();
    sum = red[8] + red[9] + red[10] + red[11];

    float inv = 1.0f / sum;
    ushort8_t pk;
#pragma unroll
    for (int j = 0; j < 8; j++) pk[j] = f2bf(e[j] * inv);
    *(ushort8_t*)(P + row * 2048 + t * 8) = pk;
}

// ---------------------------------------------------------------------------
extern "C" void kernel_launch(void* const* d_in, const int* in_sizes, int n_in,
                              void* d_out, int out_size, void* d_ws, size_t ws_size,
                              hipStream_t stream) {
    (void)in_sizes; (void)n_in; (void)out_size;
    const float* x  = (const float*)d_in[0];
    const float* Wq = (const float*)d_in[1];
    const float* bq = (const float*)d_in[2];
    const float* Wk = (const float*)d_in[3];
    const float* bk = (const float*)d_in[4];
    const float* Wv = (const float*)d_in[5];
    const float* bv = (const float*)d_in[6];
    float* out = (float*)d_out;

    const int B = 8, S = 2048, H = 1024;
    const size_t BSH = (size_t)B * S * H;   // 16,777,216
    const long long sXH = (long long)S * H; // 2,097,152

    char* p = (char*)d_ws;
    UST* qh = (UST*)p; p += BSH * 2;
    UST* ql = (UST*)p; p += BSH * 2;
    UST* kh = (UST*)p; p += BSH * 2;
    UST* kl = (UST*)p; p += BSH * 2;
    UST* vt = (UST*)p; p += BSH * 2;   // [B][H][S]

    const size_t fixed = (size_t)(p - (char*)d_ws);           // 160 MiB
    const size_t perB = (size_t)S * S * 6;                    // 24 MiB/batch
    const size_t avail = ws_size > fixed ? ws_size - fixed : 0;

    const size_t HH = (size_t)H * H;

    // tail region: split inputs (dead after projections; scores alias them)
    char* q = p;
    UST* xh  = (UST*)q; q += BSH * 2;
    UST* xl  = (UST*)q; q += BSH * 2;
    UST* wqh = (UST*)q; q += HH * 2;
    UST* wql = (UST*)q; q += HH * 2;
    UST* wkh = (UST*)q; q += HH * 2;
    UST* wkl = (UST*)q; q += HH * 2;
    UST* wvh = (UST*)q; q += HH * 2;

    dim3 blk(256);
    dim3 blk512(512);

    // 1. splits
    split_kernel<<<2048, blk, 0, stream>>>(x, xh, xl, (int)(BSH / 4));
    split_kernel<<<256, blk, 0, stream>>>(Wq, wqh, wql, (int)(HH / 4));
    split_kernel<<<256, blk, 0, stream>>>(Wk, wkh, wkl, (int)(HH / 4));
    cvt_hi_kernel<<<256, blk, 0, stream>>>(Wv, wvh, (int)(HH / 4));

    // 2. projections: q,k 3-term 256^2; v 1-term 128^2/BK64 transposed out
    dim3 gproj3(H / 256, S / 256, B);   // (4,8,8) = 256 blocks
    gemm3_256<1, true><<<gproj3, blk512, 0, stream>>>(
        xh, xl, wqh, wql, bq, qh, ql, H, H, sXH, 0, sXH);
    gemm3_256<1, true><<<gproj3, blk512, 0, stream>>>(
        xh, xl, wkh, wkl, bk, kh, kl, H, H, sXH, 0, sXH);
    dim3 gprojv(H / 128, S / 128, B);   // (8,16,8)
    gemm_bt<2, true><<<gprojv, blk, 0, stream>>>(
        xh, wvh, bv, vt, H, S, sXH, 0, (long long)H * S);

    // 3. attention per batch-group
    int g = (int)(avail / perB);
    if (g >= 1) {
        if (g > 8) g = 8;
        while (8 % g) g--;
        float* scores = (float*)p;            // aliases split bufs (dead now)
        UST* probs = (UST*)(p + (size_t)g * S * S * 4);

        for (int b0 = 0; b0 < B; b0 += g) {
            const size_t ob = (size_t)b0 * S * H;
            dim3 gsc(S / 256, S / 256, g);    // (8,8,g)
            gemm3_256<0, false><<<gsc, blk512, 0, stream>>>(
                qh + ob, ql + ob, kh + ob, kl + ob, nullptr,
                scores, nullptr, H, S, sXH, sXH, (long long)S * S);

            softmax_bf16<<<g * S, blk, 0, stream>>>(scores, probs);

            dim3 gpv(H / 128, S / 128, g);
            gemm_bt<0, false><<<gpv, blk, 0, stream>>>(
                probs, vt + (size_t)b0 * H * S, nullptr,
                out + ob, S, H,
                (long long)S * S, (long long)H * S, sXH);
        }
    } else {
        // tight-workspace fallback: per-batch row-chunked scores (256-row grain)
        int rows = (int)(avail / ((size_t)S * 6 * 256)) * 256;
        if (rows < 256) rows = 256;
        if (rows > S) rows = S;
        float* scores = (float*)p;
        UST* probs = (UST*)(p + (size_t)rows * S * 4);

        for (int b = 0; b < B; b++) {
            for (int r0 = 0; r0 < S; r0 += rows) {
                int rc = S - r0 < rows ? S - r0 : rows;
                const size_t ob = (size_t)b * S * H + (size_t)r0 * H;
                dim3 gsc(S / 256, rc / 256, 1);
                gemm3_256<0, false><<<gsc, blk512, 0, stream>>>(
                    qh + ob, ql + ob, kh + (size_t)b * S * H, kl + (size_t)b * S * H,
                    nullptr, scores, nullptr, H, S, 0, 0, 0);

                softmax_bf16<<<rc, blk, 0, stream>>>(scores, probs);

                dim3 gpv(H / 128, rc / 128, 1);
                gemm_bt<0, false><<<gpv, blk, 0, stream>>>(
                    probs, vt + (size_t)b * H * S, nullptr,
                    out + ob, S, H, 0, 0, 0);
            }
        }
    }
}